// Round 1
// baseline (405.920 us; speedup 1.0000x reference)
//
#include <hip/hip_runtime.h>
#include <stdint.h>

// HashGrid encoder + 32->128(relu)->64 MLP, fused, bf16 MFMA (16x16x32).
//
// Orientation: both GEMMs computed transposed, D = W^T * x^T, so that the
// layer-1 C/D fragment (col = lane&15 = point, row = 4*(lane>>4)+reg = hdim)
// is DIRECTLY consumable as layer-2's B fragment with the k-map
//   kappa(g,j) = 16*(j>>2) + 4*g + (j&3)   (g = lane>>4)
// -> zero cross-lane data movement between layers. A and B fragments only
// need a *shared* k-map bijection to contract correctly, so W1^T/W2^T are
// pre-packed into d_ws with exactly these maps by prep_kernel.
//
// Gather: lane (g = lane>>4, c = lane&15) handles point c of the tile and
// levels 4g..4g+3 -> its 4 float2 gathers are exactly its 8 A..B slots.

typedef __attribute__((ext_vector_type(8))) __bf16 bf16x8;
typedef __attribute__((ext_vector_type(4))) float  f32x4;
typedef __attribute__((ext_vector_type(2))) float  f32x2;

#define NTILES 65536   // 1M points / 16 per tile

// int(16 * (2048/16)**(l/15)) for l = 0..15  (matches Python double math)
__device__ const unsigned kRES[16] = {16u,22u,30u,42u,58u,80u,111u,153u,
                                      212u,294u,406u,561u,776u,1072u,1482u,2048u};

__global__ void prep_kernel(const float* __restrict__ W1, const float* __restrict__ W2,
                            short* __restrict__ w1p, short* __restrict__ w2p) {
  int tid = blockIdx.x * blockDim.x + threadIdx.x;   // 0..1535
  int l = tid & 63;
  int g = l >> 4;
  int c = l & 15;
  if (tid < 512) {
    // W1 pack: tile t covers hdims 16t+c (A row = lane&15); k slot j = feat 8g+j
    int t = tid >> 6;
    bf16x8 v;
#pragma unroll
    for (int j = 0; j < 8; ++j)
      v[j] = (__bf16)W1[(8*g + j)*128 + 16*t + c];
    *(bf16x8*)(w1p + (size_t)(t*64 + l)*8) = v;
  } else if (tid < 1536) {
    // W2 pack: e = mt*4+ks; A row = outdim 16mt+c; k slot j = hdim 32ks+kappa(g,j)
    int e = (tid - 512) >> 6;
    int mt = e >> 2, ks = e & 3;
    bf16x8 v;
#pragma unroll
    for (int j = 0; j < 8; ++j)
      v[j] = (__bf16)W2[(32*ks + 16*(j>>2) + 4*g + (j&3))*64 + 16*mt + c];
    *(bf16x8*)(w2p + (size_t)(e*64 + l)*8) = v;
  }
}

__global__ __launch_bounds__(256, 3) void hashgrid_mlp_kernel(
    const float* __restrict__ coords, const float* __restrict__ tables,
    const float* __restrict__ b1, const float* __restrict__ b2,
    const short* __restrict__ w1p, const short* __restrict__ w2p,
    float* __restrict__ out, int stride)
{
  const int l = threadIdx.x & 63;
  const int g = l >> 4;
  const int c = l & 15;

  // Per-lane level constants (levels 4g..4g+3), hoisted out of the tile loop.
  unsigned Rq[4], RRq[4], Mq[4]; float fRq[4];
#pragma unroll
  for (int q = 0; q < 4; ++q) {
    int lv = 4*g + q;
    unsigned R = kRES[lv];
    Rq[q] = R; RRq[q] = R*R; fRq[q] = (float)R;
    // levels >= 6 have T = 2^19 (mask); coarse levels: idx < R^3 = T already.
    Mq[q] = (lv >= 6) ? 0x7FFFFu : 0xFFFFFFFFu;
  }
  const float* tb = tables + ((size_t)g << 22);  // level (4g) base; +q<<20 per level

  // Resident W1^T fragments (8 tiles x 4 VGPR = 32 VGPRs).
  bf16x8 w1f[8];
#pragma unroll
  for (int t = 0; t < 8; ++t)
    w1f[t] = *(const bf16x8*)(w1p + (size_t)(t*64 + l)*8);

  f32x2 gx[4];
  auto prefetch = [&](int tile) {
    int p = tile*16 + c;
    float u0 = (coords[3*p+0] + 1.0f) * 0.5f;
    float u1 = (coords[3*p+1] + 1.0f) * 0.5f;
    float u2 = (coords[3*p+2] + 1.0f) * 0.5f;
#pragma unroll
    for (int q = 0; q < 4; ++q) {
      unsigned Rm1 = Rq[q] - 1u;
      unsigned d0 = (unsigned)(int)(u0 * fRq[q]); if (d0 > Rm1) d0 = Rm1;
      unsigned d1 = (unsigned)(int)(u1 * fRq[q]); if (d1 > Rm1) d1 = Rm1;
      unsigned d2 = (unsigned)(int)(u2 * fRq[q]); if (d2 > Rm1) d2 = Rm1;
      // uint32 wraparound matches the reference (T | 2^32 at masked levels)
      unsigned idx = (d0*RRq[q] + d1*Rq[q] + d2) & Mq[q];
      gx[q] = *(const f32x2*)(tb + ((size_t)q << 20) + (size_t)idx*2u);
    }
  };

  int tile = blockIdx.x * 4 + (threadIdx.x >> 6);
  prefetch(tile);
  while (true) {
    // Build x fragment (B of layer 1): slot j = feat 8g+j of point c.
    bf16x8 xf;
#pragma unroll
    for (int q = 0; q < 4; ++q) {
      xf[2*q]   = (__bf16)gx[q].x;
      xf[2*q+1] = (__bf16)gx[q].y;
    }
    int cur = tile;
    tile += stride;
    if (tile < NTILES) prefetch(tile);   // overlap next gathers with MLP

    // Layer 1: H^T[16 hdim x 16 pt] per tile t, C-init = b1 broadcast.
    f32x4 h[8];
#pragma unroll
    for (int t = 0; t < 8; ++t) {
      h[t] = *(const f32x4*)(b1 + 16*t + 4*g);
      h[t] = __builtin_amdgcn_mfma_f32_16x16x32_bf16(w1f[t], xf, h[t], 0, 0, 0);
    }

    // Layer 2: OUT^T[16 out x 16 pt] per mt, K = 128 in 4 steps.
    f32x4 o[4];
#pragma unroll
    for (int mt = 0; mt < 4; ++mt)
      o[mt] = *(const f32x4*)(b2 + 16*mt + 4*g);
#pragma unroll
    for (int ks = 0; ks < 4; ++ks) {
      // B' slots are lane-local: kappa(g,j)+32ks = hdim of h[2ks+(j>>2)][j&3]
      bf16x8 bp;
#pragma unroll
      for (int j = 0; j < 8; ++j) {
        float v = h[2*ks + (j>>2)][j & 3];
        v = fmaxf(v, 0.0f);               // ReLU fused here
        bp[j] = (__bf16)v;
      }
#pragma unroll
      for (int mt = 0; mt < 4; ++mt) {
        bf16x8 w2f = *(const bf16x8*)(w2p + (size_t)((mt*4 + ks)*64 + l)*8);
        o[mt] = __builtin_amdgcn_mfma_f32_16x16x32_bf16(w2f, bp, o[mt], 0, 0, 0);
      }
    }

    // Store: lane holds out[pt=c][16mt+4g .. +3] -> 4x dwordx4.
    float* op = out + (size_t)(cur*16 + c)*64 + 4*g;
#pragma unroll
    for (int mt = 0; mt < 4; ++mt)
      *(f32x4*)(op + 16*mt) = o[mt];

    if (tile >= NTILES) break;
  }
}

extern "C" void kernel_launch(void* const* d_in, const int* in_sizes, int n_in,
                              void* d_out, int out_size, void* d_ws, size_t ws_size,
                              hipStream_t stream) {
  const float* coords = (const float*)d_in[0];
  const float* tables = (const float*)d_in[1];
  const float* W1     = (const float*)d_in[2];
  const float* b1     = (const float*)d_in[3];
  const float* W2     = (const float*)d_in[4];
  const float* b2     = (const float*)d_in[5];
  float* out = (float*)d_out;

  short* w1p = (short*)d_ws;          // 8 KB  (8 tiles x 64 lanes x 16 B)
  short* w2p = w1p + 4096;            // 16 KB (16 frags x 64 lanes x 16 B)

  prep_kernel<<<6, 256, 0, stream>>>(W1, W2, w1p, w2p);

  const int blocks = 2048;            // 8192 waves, 8 tiles each (65536 tiles)
  hashgrid_mlp_kernel<<<blocks, 256, 0, stream>>>(coords, tables, b1, b2,
                                                  w1p, w2p, out, blocks*4);
}

// Round 2
// 362.132 us; speedup vs baseline: 1.1209x; 1.1209x over previous
//
#include <hip/hip_runtime.h>
#include <stdint.h>

// Two-pass HashGrid encoder + 32->128(relu)->64 MLP, bf16 MFMA (16x16x32).
//
// Pass 1 (gather_kernel): level-major block groups. At any instant the chip
// processes ~1 level, so each XCD's 4 MB L2 caches that level's (<=4 MB)
// table -> random gathers become L2 hits instead of L3/fabric misses (the
// R1 bottleneck: FETCH 1.17 GB, waves 95% stalled). Features stored packed
// bf16x2 (4 B/pt/level) in per-level planes of d_ws.
//
// Pass 2 (mlp_kernel): identical MFMA layout trick as R1 — both GEMMs are
// computed transposed so layer-1's C fragment is layer-2's B fragment with
// k-map kappa(g,j)=16*(j>>2)+4g+(j&3); W1^T/W2^T pre-packed with the same
// map by prep_kernel. x now comes from coalesced 4 B/lane streaming reads.

typedef __attribute__((ext_vector_type(8))) __bf16 bf16x8;
typedef __attribute__((ext_vector_type(4))) float  f32x4;
typedef __attribute__((ext_vector_type(2))) float  f32x2;

#define NPTS   1048576
#define NTILES 65536   // NPTS / 16

// int(16 * (2048/16)**(l/15)) for l = 0..15
__device__ const unsigned kRES[16] = {16u,22u,30u,42u,58u,80u,111u,153u,
                                      212u,294u,406u,561u,776u,1072u,1482u,2048u};

__device__ __forceinline__ unsigned pack_bf16(float x, float y) {
  __bf16 a = (__bf16)x, b = (__bf16)y;
  unsigned short ua, ub;
  __builtin_memcpy(&ua, &a, 2);
  __builtin_memcpy(&ub, &b, 2);
  return (unsigned)ua | ((unsigned)ub << 16);
}

__global__ void prep_kernel(const float* __restrict__ W1, const float* __restrict__ W2,
                            short* __restrict__ w1p, short* __restrict__ w2p) {
  int tid = blockIdx.x * blockDim.x + threadIdx.x;   // 0..1535
  int l = tid & 63;
  int g = l >> 4;
  int c = l & 15;
  if (tid < 512) {
    int t = tid >> 6;
    bf16x8 v;
#pragma unroll
    for (int j = 0; j < 8; ++j)
      v[j] = (__bf16)W1[(8*g + j)*128 + 16*t + c];
    *(bf16x8*)(w1p + (size_t)(t*64 + l)*8) = v;
  } else if (tid < 1536) {
    int e = (tid - 512) >> 6;
    int mt = e >> 2, ks = e & 3;
    bf16x8 v;
#pragma unroll
    for (int j = 0; j < 8; ++j)
      v[j] = (__bf16)W2[(32*ks + 16*(j>>2) + 4*g + (j&3))*64 + 16*mt + c];
    *(bf16x8*)(w2p + (size_t)(e*64 + l)*8) = v;
  }
}

// ---------------- Pass 1: level-phased gather ----------------
// grid = 16 levels * 1024 blocks; blocks of one level are contiguous in
// blockIdx so the resident window spans ~1 level -> table L2-resident.
__global__ __launch_bounds__(256) void gather_kernel(
    const float* __restrict__ coords, const float* __restrict__ tables,
    unsigned* __restrict__ xw)
{
  const int slot = blockIdx.x >> 10;
  const int lv = 15 - slot;                  // finest (biggest) levels first
  const unsigned R = kRES[lv];
  const float fR = (float)R;
  const unsigned RR = R * R;
  const unsigned Rm1 = R - 1u;
  // levels >= 6: T = 2^19 (mask); levels <= 5: idx < R^3 = T already.
  const unsigned M = (lv >= 6) ? 0x7FFFFu : 0xFFFFFFFFu;
  const float* tb = tables + ((size_t)lv << 20);
  unsigned* xp = xw + ((size_t)lv << 20);

  int p0 = (blockIdx.x & 1023) * 1024 + threadIdx.x;
#pragma unroll
  for (int i = 0; i < 4; ++i) {              // 4 independent gather chains
    int p = p0 + (i << 8);
    float u0 = (coords[3*p+0] + 1.0f) * 0.5f;
    float u1 = (coords[3*p+1] + 1.0f) * 0.5f;
    float u2 = (coords[3*p+2] + 1.0f) * 0.5f;
    unsigned d0 = (unsigned)(int)(u0 * fR); if (d0 > Rm1) d0 = Rm1;
    unsigned d1 = (unsigned)(int)(u1 * fR); if (d1 > Rm1) d1 = Rm1;
    unsigned d2 = (unsigned)(int)(u2 * fR); if (d2 > Rm1) d2 = Rm1;
    // uint32 wraparound matches reference (T = 2^19 divides 2^32 when masked)
    unsigned idx = (d0*RR + d1*R + d2) & M;
    f32x2 f = *(const f32x2*)(tb + (size_t)idx*2u);
    xp[p] = pack_bf16(f.x, f.y);
  }
}

// ---------------- Pass 2: streaming MFMA MLP ----------------
__global__ __launch_bounds__(256, 4) void mlp_kernel(
    const unsigned* __restrict__ xw,
    const float* __restrict__ b1, const float* __restrict__ b2,
    const short* __restrict__ w1p, const short* __restrict__ w2p,
    float* __restrict__ out, int stride)
{
  const int l = threadIdx.x & 63;
  const int g = l >> 4;
  const int c = l & 15;

  bf16x8 w1f[8];
#pragma unroll
  for (int t = 0; t < 8; ++t)
    w1f[t] = *(const bf16x8*)(w1p + (size_t)(t*64 + l)*8);

  unsigned gx[4];
  auto prefetch = [&](int tile) {
    int p = tile*16 + c;
#pragma unroll
    for (int q = 0; q < 4; ++q)
      gx[q] = xw[((size_t)(4*g + q) << 20) + p];
  };

  int tile = blockIdx.x * 4 + (threadIdx.x >> 6);
  prefetch(tile);
  while (true) {
    // x fragment: word q = packed bf16 pair of level 4g+q -> zero cvt ops
    union { bf16x8 v; unsigned u[4]; } X;
#pragma unroll
    for (int q = 0; q < 4; ++q) X.u[q] = gx[q];
    bf16x8 xf = X.v;

    int cur = tile;
    tile += stride;
    if (tile < NTILES) prefetch(tile);   // overlap next reads with MFMA

    f32x4 h[8];
#pragma unroll
    for (int t = 0; t < 8; ++t) {
      h[t] = *(const f32x4*)(b1 + 16*t + 4*g);
      h[t] = __builtin_amdgcn_mfma_f32_16x16x32_bf16(w1f[t], xf, h[t], 0, 0, 0);
    }

    f32x4 o[4];
#pragma unroll
    for (int mt = 0; mt < 4; ++mt)
      o[mt] = *(const f32x4*)(b2 + 16*mt + 4*g);
#pragma unroll
    for (int ks = 0; ks < 4; ++ks) {
      bf16x8 bp;
#pragma unroll
      for (int j = 0; j < 8; ++j) {
        float v = h[2*ks + (j>>2)][j & 3];
        v = fmaxf(v, 0.0f);               // fused ReLU
        bp[j] = (__bf16)v;
      }
#pragma unroll
      for (int mt = 0; mt < 4; ++mt) {
        bf16x8 w2f = *(const bf16x8*)(w2p + (size_t)((mt*4 + ks)*64 + l)*8);
        o[mt] = __builtin_amdgcn_mfma_f32_16x16x32_bf16(w2f, bp, o[mt], 0, 0, 0);
      }
    }

    float* op = out + (size_t)(cur*16 + c)*64 + 4*g;
#pragma unroll
    for (int mt = 0; mt < 4; ++mt)
      *(f32x4*)(op + 16*mt) = o[mt];

    if (tile >= NTILES) break;
  }
}

// ---------------- R1 fused kernel kept as fallback (ws too small) ----------
__global__ __launch_bounds__(256, 3) void hashgrid_mlp_kernel(
    const float* __restrict__ coords, const float* __restrict__ tables,
    const float* __restrict__ b1, const float* __restrict__ b2,
    const short* __restrict__ w1p, const short* __restrict__ w2p,
    float* __restrict__ out, int stride)
{
  const int l = threadIdx.x & 63;
  const int g = l >> 4;
  const int c = l & 15;

  unsigned Rq[4], RRq[4], Mq[4]; float fRq[4];
#pragma unroll
  for (int q = 0; q < 4; ++q) {
    int lv = 4*g + q;
    unsigned R = kRES[lv];
    Rq[q] = R; RRq[q] = R*R; fRq[q] = (float)R;
    Mq[q] = (lv >= 6) ? 0x7FFFFu : 0xFFFFFFFFu;
  }
  const float* tb = tables + ((size_t)g << 22);

  bf16x8 w1f[8];
#pragma unroll
  for (int t = 0; t < 8; ++t)
    w1f[t] = *(const bf16x8*)(w1p + (size_t)(t*64 + l)*8);

  f32x2 gx[4];
  auto prefetch = [&](int tile) {
    int p = tile*16 + c;
    float u0 = (coords[3*p+0] + 1.0f) * 0.5f;
    float u1 = (coords[3*p+1] + 1.0f) * 0.5f;
    float u2 = (coords[3*p+2] + 1.0f) * 0.5f;
#pragma unroll
    for (int q = 0; q < 4; ++q) {
      unsigned Rm1 = Rq[q] - 1u;
      unsigned d0 = (unsigned)(int)(u0 * fRq[q]); if (d0 > Rm1) d0 = Rm1;
      unsigned d1 = (unsigned)(int)(u1 * fRq[q]); if (d1 > Rm1) d1 = Rm1;
      unsigned d2 = (unsigned)(int)(u2 * fRq[q]); if (d2 > Rm1) d2 = Rm1;
      unsigned idx = (d0*RRq[q] + d1*Rq[q] + d2) & Mq[q];
      gx[q] = *(const f32x2*)(tb + ((size_t)q << 20) + (size_t)idx*2u);
    }
  };

  int tile = blockIdx.x * 4 + (threadIdx.x >> 6);
  prefetch(tile);
  while (true) {
    bf16x8 xf;
#pragma unroll
    for (int q = 0; q < 4; ++q) {
      xf[2*q]   = (__bf16)gx[q].x;
      xf[2*q+1] = (__bf16)gx[q].y;
    }
    int cur = tile;
    tile += stride;
    if (tile < NTILES) prefetch(tile);

    f32x4 h[8];
#pragma unroll
    for (int t = 0; t < 8; ++t) {
      h[t] = *(const f32x4*)(b1 + 16*t + 4*g);
      h[t] = __builtin_amdgcn_mfma_f32_16x16x32_bf16(w1f[t], xf, h[t], 0, 0, 0);
    }

    f32x4 o[4];
#pragma unroll
    for (int mt = 0; mt < 4; ++mt)
      o[mt] = *(const f32x4*)(b2 + 16*mt + 4*g);
#pragma unroll
    for (int ks = 0; ks < 4; ++ks) {
      bf16x8 bp;
#pragma unroll
      for (int j = 0; j < 8; ++j) {
        float v = h[2*ks + (j>>2)][j & 3];
        v = fmaxf(v, 0.0f);
        bp[j] = (__bf16)v;
      }
#pragma unroll
      for (int mt = 0; mt < 4; ++mt) {
        bf16x8 w2f = *(const bf16x8*)(w2p + (size_t)((mt*4 + ks)*64 + l)*8);
        o[mt] = __builtin_amdgcn_mfma_f32_16x16x32_bf16(w2f, bp, o[mt], 0, 0, 0);
      }
    }

    float* op = out + (size_t)(cur*16 + c)*64 + 4*g;
#pragma unroll
    for (int mt = 0; mt < 4; ++mt)
      *(f32x4*)(op + 16*mt) = o[mt];

    if (tile >= NTILES) break;
  }
}

extern "C" void kernel_launch(void* const* d_in, const int* in_sizes, int n_in,
                              void* d_out, int out_size, void* d_ws, size_t ws_size,
                              hipStream_t stream) {
  const float* coords = (const float*)d_in[0];
  const float* tables = (const float*)d_in[1];
  const float* W1     = (const float*)d_in[2];
  const float* b1     = (const float*)d_in[3];
  const float* W2     = (const float*)d_in[4];
  const float* b2     = (const float*)d_in[5];
  float* out = (float*)d_out;

  short* w1p = (short*)d_ws;          // 8 KB
  short* w2p = w1p + 4096;            // 16 KB
  prep_kernel<<<6, 256, 0, stream>>>(W1, W2, w1p, w2p);

  const size_t need = 32*1024 + (size_t)NPTS * 16 * 4;   // 64 MB + 32 KB
  const int blocks = 2048;
  if (ws_size >= need) {
    unsigned* xw = (unsigned*)((char*)d_ws + 32*1024);
    gather_kernel<<<16*1024, 256, 0, stream>>>(coords, tables, xw);
    mlp_kernel<<<blocks, 256, 0, stream>>>(xw, b1, b2, w1p, w2p, out, blocks*4);
  } else {
    hashgrid_mlp_kernel<<<blocks, 256, 0, stream>>>(coords, tables, b1, b2,
                                                    w1p, w2p, out, blocks*4);
  }
}